// Round 6
// baseline (704.804 us; speedup 1.0000x reference)
//
#include <hip/hip_runtime.h>

// B=256, N=196, C=256, H=8, KD=32, VD=64, Q=49, R=14
#define EPS 1e-5f
#define QK_SCALE 0.17677669529663687f

typedef __attribute__((ext_vector_type(8))) short bf16x8;   // 8 bf16 = 4 VGPRs
typedef __attribute__((ext_vector_type(4))) float f32x4;

__device__ inline unsigned short bf16_rne(float f) {
    unsigned int u = __float_as_uint(f);
    u = u + 0x7FFFu + ((u >> 16) & 1u);
    return (unsigned short)(u >> 16);
}
__device__ inline float bf16_f(unsigned short s) {
    return __uint_as_float(((unsigned int)s) << 16);
}
__device__ inline void split1(float v, unsigned short& hi, unsigned short& lo) {
    hi = bf16_rne(v); lo = bf16_rne(v - bf16_f(hi));
}
__device__ inline void split4(float4 v, ushort4& hi, ushort4& lo) {
    hi.x = bf16_rne(v.x); hi.y = bf16_rne(v.y); hi.z = bf16_rne(v.z); hi.w = bf16_rne(v.w);
    lo.x = bf16_rne(v.x - bf16_f(hi.x));
    lo.y = bf16_rne(v.y - bf16_f(hi.y));
    lo.z = bf16_rne(v.z - bf16_f(hi.z));
    lo.w = bf16_rne(v.w - bf16_f(hi.w));
}
__device__ inline void split8(float4 a, float4 b, bf16x8& hi, bf16x8& lo) {
    ushort4 h0, l0, h1, l1;
    split4(a, h0, l0); split4(b, h1, l1);
    union { ushort4 u4[2]; bf16x8 v; } H, L;
    H.u4[0] = h0; H.u4[1] = h1; L.u4[0] = l0; L.u4[1] = l1;
    hi = H.v; lo = L.v;
}

#define MFMA16(a, b, c) __builtin_amdgcn_mfma_f32_16x16x32_bf16((a), (b), (c), 0, 0, 0)

// ---------- prep: split weights to bf16 hi/lo planes in ws (runs every launch)
// wb[h][128][256]: j<96 -> kv_w[h*96+j], j>=96 -> q_w[h*32+j-96]; pw[384][512]
__global__ __launch_bounds__(256)
void prep_split(const float* __restrict__ kv_w, const float* __restrict__ q_w,
                const float* __restrict__ pw,
                unsigned short* __restrict__ wb_hi, unsigned short* __restrict__ wb_lo,
                unsigned short* __restrict__ pw_hi, unsigned short* __restrict__ pw_lo)
{
    int i = blockIdx.x * 256 + threadIdx.x;
    if (i < 262144) {
        int c = i & 255, j = (i >> 8) & 127, h = i >> 15;
        float v = (j < 96) ? kv_w[(h * 96 + j) * 256 + c]
                           : q_w[(h * 32 + (j - 96)) * 256 + c];
        unsigned short hi, lo; split1(v, hi, lo);
        wb_hi[i] = hi; wb_lo[i] = lo;
    } else {
        int p = i - 262144;
        if (p < 196608) {
            float v = pw[p];
            unsigned short hi, lo; split1(v, hi, lo);
            pw_hi[p] = hi; pw_lo[p] = lo;
        }
    }
}

// ---------- fused attn: 1024 threads (16 waves, 4/SIMD), 1 block/CU
// LDS 163,088 B: K[208][40]x2 | Q[64][40]x2 | V[64][232]x2 | P[64][232]x2 | bias
// GEMM1: no LDS staging, no K-loop barriers. Wave w (<13) owns rows 16w..16w+15,
// all 8 col tiles. QK: waves 0..3. PV: 16 waves, 1 tile each. 2 barriers total.
__global__ __launch_bounds__(1024, 4)
void levit_fused_attn(const float* __restrict__ x,
                      const unsigned short* __restrict__ wb_hi,
                      const unsigned short* __restrict__ wb_lo,
                      const float* __restrict__ kv_g, const float* __restrict__ kv_b,
                      const float* __restrict__ kv_m, const float* __restrict__ kv_v,
                      const float* __restrict__ q_g, const float* __restrict__ q_b,
                      const float* __restrict__ q_m, const float* __restrict__ q_v,
                      const float* __restrict__ attn_bias,
                      unsigned short* __restrict__ ao_hi,
                      unsigned short* __restrict__ ao_lo)
{
    __shared__ __align__(16) unsigned short s_k[2 * 208 * 40];
    __shared__ __align__(16) unsigned short s_q[2 * 64 * 40];
    __shared__ __align__(16) unsigned short s_v[2 * 64 * 232];
    __shared__ __align__(16) unsigned short s_p[2 * 64 * 232];
    __shared__ float bias_s[196];

    unsigned short* s_khi = s_k;             unsigned short* s_klo = s_k + 208 * 40;
    unsigned short* s_qhi = s_q;             unsigned short* s_qlo = s_q + 64 * 40;
    unsigned short* s_vhi = s_v;             unsigned short* s_vlo = s_v + 64 * 232;
    unsigned short* s_phi = s_p;             unsigned short* s_plo = s_p + 64 * 232;

    const int t = threadIdx.x;
    const int b = blockIdx.x;       // linear id = b + 256*hh -> same-b heads on one XCD
    const int hh = blockIdx.y;

    const int l = t & 63;
    const int w = t >> 6;           // 16 waves
    const int lrow = l & 15;
    const int kg = (l >> 4) * 8;    // k offset of this quarter-wave
    const int g4 = (l >> 4) * 4;    // C-layout row group

    if (t < 196) bias_s[t] = attn_bias[hh * 196 + t];
    // zero V pad cols 196..231 and P pad cols 208..231 (block NaN: P=0 x junk)
    for (int i = t; i < 64 * 36; i += 1024) {
        int r = i / 36, c = 196 + i % 36;
        s_vhi[r * 232 + c] = 0; s_vlo[r * 232 + c] = 0;
    }
    for (int i = t; i < 64 * 24; i += 1024) {
        int r = i / 24, c = 208 + i % 24;
        s_phi[r * 232 + c] = 0; s_plo[r * 232 + c] = 0;
    }

    // ---------------- GEMM1 (no barriers): [208x128] = x @ [kv_w;q_w]^T
    if (w < 13) {
        int n = 16 * w + lrow; if (n > 195) n = 195;   // junk rows masked at scatter
        const float* xrow = &x[(b * 196 + n) * 256];
        const unsigned short* wbh = &wb_hi[(hh * 128 + lrow) * 256];
        const unsigned short* wbl = &wb_lo[(hh * 128 + lrow) * 256];

        f32x4 acc[8];
        #pragma unroll
        for (int i = 0; i < 8; ++i) acc[i] = (f32x4){0.f, 0.f, 0.f, 0.f};

        #pragma unroll 2
        for (int kc = 0; kc < 256; kc += 32) {
            float4 xa = *(const float4*)&xrow[kc + kg];
            float4 xb = *(const float4*)&xrow[kc + kg + 4];
            bf16x8 ah, al; split8(xa, xb, ah, al);
            #pragma unroll
            for (int ct = 0; ct < 8; ++ct) {
                bf16x8 bh = *(const bf16x8*)&wbh[ct * 16 * 256 + kc + kg];
                bf16x8 bl = *(const bf16x8*)&wbl[ct * 16 * 256 + kc + kg];
                acc[ct] = MFMA16(ah, bh, acc[ct]);
                acc[ct] = MFMA16(ah, bl, acc[ct]);
                acc[ct] = MFMA16(al, bh, acc[ct]);
            }
        }

        // epilogue: norm + split-bf16 scatter to K[n][d] / vT[vd][n] / Q[qi][d]
        const int nb = 16 * w + g4;       // 4 consecutive rows nb..nb+3
        #pragma unroll
        for (int ct = 0; ct < 8; ++ct) {
            int j = 16 * ct + lrow;
            float gg, bb, mm, vv;
            if (ct < 6) { int col = hh * 96 + j;        gg = kv_g[col]; bb = kv_b[col]; mm = kv_m[col]; vv = kv_v[col]; }
            else        { int col = hh * 32 + (j - 96); gg = q_g[col];  bb = q_b[col];  mm = q_m[col];  vv = q_v[col]; }
            float ivv = gg * rsqrtf(vv + EPS);
            float bee = bb - mm * ivv;
            unsigned short his[4], los[4];
            #pragma unroll
            for (int reg = 0; reg < 4; ++reg) {
                float val = acc[ct][reg] * ivv + bee;
                split1(val, his[reg], los[reg]);
            }
            if (nb < 196) {
                if (ct < 2) {
                    #pragma unroll
                    for (int reg = 0; reg < 4; ++reg) {
                        s_khi[(nb + reg) * 40 + j] = his[reg];
                        s_klo[(nb + reg) * 40 + j] = los[reg];
                    }
                } else if (ct < 6) {
                    int vd = j - 32;
                    ushort4 h4 = {his[0], his[1], his[2], his[3]};
                    ushort4 l4 = {los[0], los[1], los[2], los[3]};
                    *(ushort4*)&s_vhi[vd * 232 + nb] = h4;
                    *(ushort4*)&s_vlo[vd * 232 + nb] = l4;
                } else {
                    #pragma unroll
                    for (int reg = 0; reg < 4; ++reg) {
                        int n2 = nb + reg;
                        int a = n2 / 28, rem = n2 - 28 * a;
                        if (rem < 14 && !(rem & 1)) {
                            int qi = a * 7 + (rem >> 1);
                            s_qhi[qi * 40 + (j - 96)] = his[reg];
                            s_qlo[qi * 40 + (j - 96)] = los[reg];
                        }
                    }
                }
            }
        }
    }
    __syncthreads();   // K/Q/V (+pads) ready

    // ---------------- QK + softmax (waves 0..3; wave owns M-tile mt=w, full rows)
    if (w < 4) {
        const int mt = w;
        bf16x8 qh = *(const bf16x8*)&s_qhi[(16 * mt + lrow) * 40 + kg];
        bf16x8 ql = *(const bf16x8*)&s_qlo[(16 * mt + lrow) * 40 + kg];
        f32x4 sv[13];
        #pragma unroll
        for (int nt = 0; nt < 13; ++nt) {
            bf16x8 kh = *(const bf16x8*)&s_khi[(16 * nt + lrow) * 40 + kg];
            bf16x8 kl = *(const bf16x8*)&s_klo[(16 * nt + lrow) * 40 + kg];
            f32x4 a = {0.f, 0.f, 0.f, 0.f};
            a = MFMA16(qh, kh, a);
            a = MFMA16(qh, kl, a);
            a = MFMA16(ql, kh, a);
            sv[nt] = a;
        }
        const int m_base = 16 * mt + g4;
        float lmax[4] = {-3.0e38f, -3.0e38f, -3.0e38f, -3.0e38f};
        #pragma unroll
        for (int reg = 0; reg < 4; ++reg) {
            int m = m_base + reg;
            int mq = m < 49 ? m : 48;
            int yq = (mq / 7) * 2, xq2 = (mq % 7) * 2;
            #pragma unroll
            for (int nt = 0; nt < 13; ++nt) {
                int n = 16 * nt + lrow;
                float s;
                if (n < 196) {
                    int yk = n / 14, xk = n - 14 * yk;
                    int r0 = yq >= yk ? yq - yk : yk - yq;
                    int r1 = xq2 >= xk ? xq2 - xk : xk - xq2;
                    s = sv[nt][reg] * QK_SCALE + bias_s[r0 * 14 + r1];
                } else {
                    s = -1.0e30f;   // assignment erases any junk-K NaN
                }
                sv[nt][reg] = s;
                lmax[reg] = fmaxf(lmax[reg], s);
            }
        }
        #pragma unroll
        for (int off = 1; off < 16; off <<= 1)
            #pragma unroll
            for (int reg = 0; reg < 4; ++reg)
                lmax[reg] = fmaxf(lmax[reg], __shfl_xor(lmax[reg], off, 64));
        float rsum[4] = {0.f, 0.f, 0.f, 0.f};
        #pragma unroll
        for (int nt = 0; nt < 13; ++nt)
            #pragma unroll
            for (int reg = 0; reg < 4; ++reg) {
                float p = __expf(sv[nt][reg] - lmax[reg]);
                sv[nt][reg] = p;
                rsum[reg] += p;
            }
        #pragma unroll
        for (int off = 1; off < 16; off <<= 1)
            #pragma unroll
            for (int reg = 0; reg < 4; ++reg)
                rsum[reg] += __shfl_xor(rsum[reg], off, 64);
        float rinv[4];
        #pragma unroll
        for (int reg = 0; reg < 4; ++reg) rinv[reg] = 1.f / rsum[reg];
        #pragma unroll
        for (int nt = 0; nt < 13; ++nt)
            #pragma unroll
            for (int reg = 0; reg < 4; ++reg) {
                float pn = sv[nt][reg] * rinv[reg];
                unsigned short hi, lo; split1(pn, hi, lo);
                int row = m_base + reg, col = 16 * nt + lrow;
                s_phi[row * 232 + col] = hi;
                s_plo[row * 232 + col] = lo;
            }
    }
    __syncthreads();   // P ready

    // ---------------- PV (16 waves, exactly 1 tile each)
    {
        const int mtv = w & 3;
        const int ntv = w >> 2;
        f32x4 pacc = {0.f, 0.f, 0.f, 0.f};
        #pragma unroll
        for (int s = 0; s < 7; ++s) {
            bf16x8 ph = *(const bf16x8*)&s_phi[(16 * mtv + lrow) * 232 + 32 * s + kg];
            bf16x8 pl = *(const bf16x8*)&s_plo[(16 * mtv + lrow) * 232 + 32 * s + kg];
            bf16x8 vh = *(const bf16x8*)&s_vhi[(16 * ntv + lrow) * 232 + 32 * s + kg];
            bf16x8 vl = *(const bf16x8*)&s_vlo[(16 * ntv + lrow) * 232 + 32 * s + kg];
            pacc = MFMA16(ph, vh, pacc);
            pacc = MFMA16(ph, vl, pacc);
            pacc = MFMA16(pl, vh, pacc);
        }
        const int vd = 16 * ntv + lrow;
        #pragma unroll
        for (int reg = 0; reg < 4; ++reg) {
            int r = 16 * mtv + g4 + reg;
            if (r < 49) {
                float v = pacc[reg];
                float hs = v * fminf(fmaxf(v + 3.f, 0.f), 6.f) * (1.f / 6.f);
                unsigned short hi, lo; split1(hs, hi, lo);
                int idx = ((b * 49 + r) * 8 + hh) * 64 + vd;
                ao_hi[idx] = hi;
                ao_lo[idx] = lo;
            }
        }
    }
}

// ---------- proj: out = linear_norm(hs_pre_applied(A), pw)  [12544x512]@[512x384]^T
// Zero LDS, zero barriers: direct global frag loads (A pre-split in ws, W pre-split).
// Block 512 thr: wave (mt = w&3) x col-half (nh = w>>2, 4 nt tiles). Grid (3, 256).
__global__ __launch_bounds__(512, 4)
void levit_proj(const unsigned short* __restrict__ ao_hi,
                const unsigned short* __restrict__ ao_lo,
                const unsigned short* __restrict__ pw_hi,
                const unsigned short* __restrict__ pw_lo,
                const float* __restrict__ pg, const float* __restrict__ pb,
                const float* __restrict__ pm, const float* __restrict__ pv,
                float* __restrict__ out)
{
    const int t = threadIdx.x;
    const int cg = blockIdx.x;       // 0..2 (128 output cols each)
    const int b = blockIdx.y;
    const int l = t & 63;
    const int w = t >> 6;
    const int lrow = l & 15;
    const int kg = (l >> 4) * 8;
    const int g4 = (l >> 4) * 4;
    const int mt = w & 3;
    const int nh = w >> 2;

    int r0 = 16 * mt + lrow;
    int rc = b * 49 + (r0 < 49 ? r0 : 48);   // clamp junk rows (masked at store)
    const unsigned short* ap_h = &ao_hi[rc * 512];
    const unsigned short* ap_l = &ao_lo[rc * 512];
    const unsigned short* wp_h = &pw_hi[(cg * 128 + 64 * nh + lrow) * 512];
    const unsigned short* wp_l = &pw_lo[(cg * 128 + 64 * nh + lrow) * 512];

    f32x4 acc[4];
    #pragma unroll
    for (int i = 0; i < 4; ++i) acc[i] = (f32x4){0.f, 0.f, 0.f, 0.f};

    #pragma unroll 2
    for (int kc = 0; kc < 512; kc += 32) {
        bf16x8 ah = *(const bf16x8*)&ap_h[kc + kg];
        bf16x8 al = *(const bf16x8*)&ap_l[kc + kg];
        #pragma unroll
        for (int i = 0; i < 4; ++i) {
            bf16x8 bh = *(const bf16x8*)&wp_h[i * 16 * 512 + kc + kg];
            bf16x8 bl = *(const bf16x8*)&wp_l[i * 16 * 512 + kc + kg];
            acc[i] = MFMA16(ah, bh, acc[i]);
            acc[i] = MFMA16(ah, bl, acc[i]);
            acc[i] = MFMA16(al, bh, acc[i]);
        }
    }

    #pragma unroll
    for (int i = 0; i < 4; ++i) {
        int o = cg * 128 + 64 * nh + 16 * i + lrow;
        float iv = pg[o] * rsqrtf(pv[o] + EPS);
        float be = pb[o] - pm[o] * iv;
        #pragma unroll
        for (int reg = 0; reg < 4; ++reg) {
            int r = 16 * mt + g4 + reg;
            if (r < 49) out[(b * 49 + r) * 384 + o] = acc[i][reg] * iv + be;
        }
    }
}

extern "C" void kernel_launch(void* const* d_in, const int* in_sizes, int n_in,
                              void* d_out, int out_size, void* d_ws, size_t ws_size,
                              hipStream_t stream) {
    const float* x     = (const float*)d_in[0];
    const float* kv_w  = (const float*)d_in[1];
    const float* kv_g  = (const float*)d_in[2];
    const float* kv_b  = (const float*)d_in[3];
    const float* kv_m  = (const float*)d_in[4];
    const float* kv_v  = (const float*)d_in[5];
    const float* q_g   = (const float*)d_in[7];
    const float* q_b   = (const float*)d_in[8];
    const float* q_m   = (const float*)d_in[9];
    const float* q_v   = (const float*)d_in[10];
    const float* q_wp  = (const float*)d_in[6];
    const float* pw    = (const float*)d_in[11];
    const float* pg    = (const float*)d_in[12];
    const float* pb    = (const float*)d_in[13];
    const float* pm    = (const float*)d_in[14];
    const float* pv    = (const float*)d_in[15];
    const float* ab    = (const float*)d_in[16];

    // ws layout (27.5 MB):
    unsigned short* ao_hi = (unsigned short*)d_ws;                 // 12544*512
    unsigned short* ao_lo = ao_hi + 12544 * 512;                   // 12544*512
    unsigned short* wb_hi = ao_lo + 12544 * 512;                   // 8*128*256
    unsigned short* wb_lo = wb_hi + 262144;
    unsigned short* pw_hi = wb_lo + 262144;                        // 384*512
    unsigned short* pw_lo = pw_hi + 196608;

    prep_split<<<1792, 256, 0, stream>>>(kv_w, q_wp, pw, wb_hi, wb_lo, pw_hi, pw_lo);

    dim3 g1(256, 8);   // linear id = b + 256*hh -> same-b heads share an XCD
    levit_fused_attn<<<g1, 1024, 0, stream>>>(x, wb_hi, wb_lo,
                                              kv_g, kv_b, kv_m, kv_v,
                                              q_g, q_b, q_m, q_v, ab, ao_hi, ao_lo);
    levit_proj<<<dim3(3, 256), 512, 0, stream>>>(ao_hi, ao_lo, pw_hi, pw_lo,
                                                 pg, pb, pm, pv, (float*)d_out);
}

// Round 7
// 368.484 us; speedup vs baseline: 1.9127x; 1.9127x over previous
//
#include <hip/hip_runtime.h>

// B=256, N=196, C=256, H=8, KD=32, VD=64, Q=49, R=14
#define EPS 1e-5f
#define QK_SCALE 0.17677669529663687f

typedef __attribute__((ext_vector_type(8))) short bf16x8;   // 8 bf16 = 4 VGPRs
typedef __attribute__((ext_vector_type(4))) float f32x4;

__device__ inline unsigned short bf16_rne(float f) {
    unsigned int u = __float_as_uint(f);
    u = u + 0x7FFFu + ((u >> 16) & 1u);
    return (unsigned short)(u >> 16);
}
__device__ inline float bf16_f(unsigned short s) {
    return __uint_as_float(((unsigned int)s) << 16);
}
__device__ inline void split1(float v, unsigned short& hi, unsigned short& lo) {
    hi = bf16_rne(v); lo = bf16_rne(v - bf16_f(hi));
}
__device__ inline void split4(float4 v, ushort4& hi, ushort4& lo) {
    hi.x = bf16_rne(v.x); hi.y = bf16_rne(v.y); hi.z = bf16_rne(v.z); hi.w = bf16_rne(v.w);
    lo.x = bf16_rne(v.x - bf16_f(hi.x));
    lo.y = bf16_rne(v.y - bf16_f(hi.y));
    lo.z = bf16_rne(v.z - bf16_f(hi.z));
    lo.w = bf16_rne(v.w - bf16_f(hi.w));
}

#define MFMA16(a, b, c) __builtin_amdgcn_mfma_f32_16x16x32_bf16((a), (b), (c), 0, 0, 0)

// ---------- prep: split weights to bf16 hi/lo planes in ws
// wb[h][128][256]: j<96 -> kv_w[h*96+j], j>=96 -> q_w[h*32+j-96]; pw[384][512]
__global__ __launch_bounds__(256)
void prep_split(const float* __restrict__ kv_w, const float* __restrict__ q_w,
                const float* __restrict__ pw,
                unsigned short* __restrict__ wb_hi, unsigned short* __restrict__ wb_lo,
                unsigned short* __restrict__ pw_hi, unsigned short* __restrict__ pw_lo)
{
    int i = blockIdx.x * 256 + threadIdx.x;
    if (i < 262144) {
        int c = i & 255, j = (i >> 8) & 127, h = i >> 15;
        float v = (j < 96) ? kv_w[(h * 96 + j) * 256 + c]
                           : q_w[(h * 32 + (j - 96)) * 256 + c];
        unsigned short hi, lo; split1(v, hi, lo);
        wb_hi[i] = hi; wb_lo[i] = lo;
    } else {
        int p = i - 262144;
        if (p < 196608) {
            float v = pw[p];
            unsigned short hi, lo; split1(v, hi, lo);
            pw_hi[p] = hi; pw_lo[p] = lo;
        }
    }
}

// ---------- fused attn: 1024 thr (16 waves, 4/SIMD), 1 block/CU, LDS-staged GEMM1
// LDS 163,088 B: un(staging x[208][40]x2 + w[128][40]x2  UNION  P[64][232]x2)
//                | K[208][40]x2 | Q[64][40]x2 | V[64][232]x2 | bias
__global__ __launch_bounds__(1024, 4)
void levit_fused_attn(const float* __restrict__ x,
                      const unsigned short* __restrict__ wb_hi,
                      const unsigned short* __restrict__ wb_lo,
                      const float* __restrict__ kv_g, const float* __restrict__ kv_b,
                      const float* __restrict__ kv_m, const float* __restrict__ kv_v,
                      const float* __restrict__ q_g, const float* __restrict__ q_b,
                      const float* __restrict__ q_m, const float* __restrict__ q_v,
                      const float* __restrict__ attn_bias,
                      unsigned short* __restrict__ ao_hi,
                      unsigned short* __restrict__ ao_lo)
{
    __shared__ __align__(16) unsigned short s_un[29696];   // staging UNION P (59,392 B)
    __shared__ __align__(16) unsigned short s_k[16640];
    __shared__ __align__(16) unsigned short s_q[5120];
    __shared__ __align__(16) unsigned short s_v[29696];
    __shared__ float bias_s[196];

    unsigned short* s_xhi = s_un;                  // [208][40]
    unsigned short* s_xlo = s_un + 8320;
    unsigned short* s_whi = s_un + 16640;          // [128][40]
    unsigned short* s_wlo = s_un + 21760;
    unsigned short* s_phi = s_un;                  // [64][232] (post-GEMM union)
    unsigned short* s_plo = s_un + 14848;
    unsigned short* s_khi = s_k;                   // [208][40]
    unsigned short* s_klo = s_k + 8320;
    unsigned short* s_qhi = s_q;                   // [64][40]
    unsigned short* s_qlo = s_q + 2560;
    unsigned short* s_vhi = s_v;                   // [64][232]
    unsigned short* s_vlo = s_v + 14848;

    const int t = threadIdx.x;
    const int b = blockIdx.x;       // linear id = b + 256*hh -> same-b heads on one XCD
    const int hh = blockIdx.y;

    const int l = t & 63;
    const int w = t >> 6;           // 16 waves
    const int rg = w & 3;           // row-tiles rt = rg + 4i (i<4, rt<13)
    const int cg = w >> 2;          // col-tiles 2cg, 2cg+1
    const int lrow = l & 15;
    const int kg = (l >> 4) * 8;
    const int g4 = (l >> 4) * 4;

    if (t < 196) bias_s[t] = attn_bias[hh * 196 + t];
    // zero V pad cols 196..231 (blocks NaN: P=0 x junk)
    for (int i = t; i < 64 * 36; i += 1024) {
        int r = i / 36, c = 196 + i % 36;
        s_vhi[r * 232 + c] = 0; s_vlo[r * 232 + c] = 0;
    }

    // ---------------- GEMM1: [208x128] = x @ [kv_w;q_w]^T (LDS-staged, 16 waves)
    f32x4 acc[4][2];
    #pragma unroll
    for (int i = 0; i < 4; ++i) { acc[i][0] = (f32x4){0,0,0,0}; acc[i][1] = (f32x4){0,0,0,0}; }

    for (int kc = 0; kc < 256; kc += 32) {
        __syncthreads();
        #pragma unroll
        for (int it = 0; it < 2; ++it) {          // x: 208 rows x 8 f4 = 1664
            int f = t + 1024 * it;
            if (f < 208 * 8) {
                int n = f >> 3, c4 = (f & 7) * 4;
                float4 v = {0.f, 0.f, 0.f, 0.f};
                if (n < 196) v = *(const float4*)&x[(b * 196 + n) * 256 + kc + c4];
                ushort4 vh, vl; split4(v, vh, vl);
                *(ushort4*)&s_xhi[n * 40 + c4] = vh;
                *(ushort4*)&s_xlo[n * 40 + c4] = vl;
            }
        }
        {                                          // w: 128 rows x 4 b128 x 2 planes = 1024
            int plane = t >> 9, rem = t & 511;
            int j = rem >> 2, c8 = (rem & 3) * 8;
            const unsigned short* src = plane ? wb_lo : wb_hi;
            unsigned short* dst = plane ? s_wlo : s_whi;
            *(bf16x8*)&dst[j * 40 + c8] =
                *(const bf16x8*)&src[(hh * 128 + j) * 256 + kc + c8];
        }
        __syncthreads();

        bf16x8 bh[2], bl[2];
        #pragma unroll
        for (int ctl = 0; ctl < 2; ++ctl) {
            int jr = 16 * (2 * cg + ctl) + lrow;
            bh[ctl] = *(const bf16x8*)&s_whi[jr * 40 + kg];
            bl[ctl] = *(const bf16x8*)&s_wlo[jr * 40 + kg];
        }
        #pragma unroll
        for (int i = 0; i < 4; ++i) {
            int rt = rg + 4 * i;
            if (rt < 13) {                         // wave-uniform
                int arow = 16 * rt + lrow;
                bf16x8 ah = *(const bf16x8*)&s_xhi[arow * 40 + kg];
                bf16x8 al = *(const bf16x8*)&s_xlo[arow * 40 + kg];
                #pragma unroll
                for (int ctl = 0; ctl < 2; ++ctl) {
                    acc[i][ctl] = MFMA16(ah, bh[ctl], acc[i][ctl]);
                    acc[i][ctl] = MFMA16(ah, bl[ctl], acc[i][ctl]);
                    acc[i][ctl] = MFMA16(al, bh[ctl], acc[i][ctl]);
                }
            }
        }
    }

    // epilogue: norm + split-bf16 scatter to K[n][d] / vT[vd][n] / Q[qi][d]
    #pragma unroll
    for (int ctl = 0; ctl < 2; ++ctl) {
        int ct = 2 * cg + ctl;
        int j = 16 * ct + lrow;
        float gg, bb, mm, vv;
        if (ct < 6) { int col = hh * 96 + j;        gg = kv_g[col]; bb = kv_b[col]; mm = kv_m[col]; vv = kv_v[col]; }
        else        { int col = hh * 32 + (j - 96); gg = q_g[col];  bb = q_b[col];  mm = q_m[col];  vv = q_v[col]; }
        float ivv = gg * rsqrtf(vv + EPS);
        float bee = bb - mm * ivv;
        #pragma unroll
        for (int i = 0; i < 4; ++i) {
            int rt = rg + 4 * i;
            if (rt < 13) {
                int nb = 16 * rt + g4;             // rows nb..nb+3 (nb % 4 == 0)
                if (nb < 196) {
                    unsigned short his[4], los[4];
                    #pragma unroll
                    for (int reg = 0; reg < 4; ++reg)
                        split1(acc[i][ctl][reg] * ivv + bee, his[reg], los[reg]);
                    if (ct < 2) {
                        #pragma unroll
                        for (int reg = 0; reg < 4; ++reg) {
                            s_khi[(nb + reg) * 40 + j] = his[reg];
                            s_klo[(nb + reg) * 40 + j] = los[reg];
                        }
                    } else if (ct < 6) {
                        int vd = j - 32;
                        ushort4 h4 = {his[0], his[1], his[2], his[3]};
                        ushort4 l4 = {los[0], los[1], los[2], los[3]};
                        *(ushort4*)&s_vhi[vd * 232 + nb] = h4;
                        *(ushort4*)&s_vlo[vd * 232 + nb] = l4;
                    } else {
                        #pragma unroll
                        for (int reg = 0; reg < 4; ++reg) {
                            int n2 = nb + reg;
                            int a = n2 / 28, rem = n2 - 28 * a;
                            if (rem < 14 && !(rem & 1)) {
                                int qi = a * 7 + (rem >> 1);
                                s_qhi[qi * 40 + (j - 96)] = his[reg];
                                s_qlo[qi * 40 + (j - 96)] = los[reg];
                            }
                        }
                    }
                }
            }
        }
    }
    __syncthreads();   // staging dead; K/Q/V ready; P region free

    // zero P pad cols 208..231
    for (int i = t; i < 64 * 24; i += 1024) {
        int r = i / 24, c = 208 + i % 24;
        s_phi[r * 232 + c] = 0; s_plo[r * 232 + c] = 0;
    }

    // ---------------- QK + softmax (waves 0..3; wave owns M-tile mt=w)
    if (w < 4) {
        const int mt = w;
        bf16x8 qh = *(const bf16x8*)&s_qhi[(16 * mt + lrow) * 40 + kg];
        bf16x8 ql = *(const bf16x8*)&s_qlo[(16 * mt + lrow) * 40 + kg];
        f32x4 sv[13];
        #pragma unroll
        for (int nt = 0; nt < 13; ++nt) {
            bf16x8 kh = *(const bf16x8*)&s_khi[(16 * nt + lrow) * 40 + kg];
            bf16x8 kl = *(const bf16x8*)&s_klo[(16 * nt + lrow) * 40 + kg];
            f32x4 a = {0.f, 0.f, 0.f, 0.f};
            a = MFMA16(qh, kh, a);
            a = MFMA16(qh, kl, a);
            a = MFMA16(ql, kh, a);
            sv[nt] = a;
        }
        const int m_base = 16 * mt + g4;
        float lmax[4] = {-3.0e38f, -3.0e38f, -3.0e38f, -3.0e38f};
        #pragma unroll
        for (int reg = 0; reg < 4; ++reg) {
            int m = m_base + reg;
            int mq = m < 49 ? m : 48;
            int yq = (mq / 7) * 2, xq2 = (mq % 7) * 2;
            #pragma unroll
            for (int nt = 0; nt < 13; ++nt) {
                int n = 16 * nt + lrow;
                float s;
                if (n < 196) {
                    int yk = n / 14, xk = n - 14 * yk;
                    int r0 = yq >= yk ? yq - yk : yk - yq;
                    int r1 = xq2 >= xk ? xq2 - xk : xk - xq2;
                    s = sv[nt][reg] * QK_SCALE + bias_s[r0 * 14 + r1];
                } else {
                    s = -1.0e30f;
                }
                sv[nt][reg] = s;
                lmax[reg] = fmaxf(lmax[reg], s);
            }
        }
        #pragma unroll
        for (int off = 1; off < 16; off <<= 1)
            #pragma unroll
            for (int reg = 0; reg < 4; ++reg)
                lmax[reg] = fmaxf(lmax[reg], __shfl_xor(lmax[reg], off, 64));
        float rsum[4] = {0.f, 0.f, 0.f, 0.f};
        #pragma unroll
        for (int nt = 0; nt < 13; ++nt)
            #pragma unroll
            for (int reg = 0; reg < 4; ++reg) {
                float p = __expf(sv[nt][reg] - lmax[reg]);
                sv[nt][reg] = p;
                rsum[reg] += p;
            }
        #pragma unroll
        for (int off = 1; off < 16; off <<= 1)
            #pragma unroll
            for (int reg = 0; reg < 4; ++reg)
                rsum[reg] += __shfl_xor(rsum[reg], off, 64);
        float rinv[4];
        #pragma unroll
        for (int reg = 0; reg < 4; ++reg) rinv[reg] = 1.f / rsum[reg];
        #pragma unroll
        for (int nt = 0; nt < 13; ++nt)
            #pragma unroll
            for (int reg = 0; reg < 4; ++reg) {
                float pn = sv[nt][reg] * rinv[reg];
                unsigned short hi, lo; split1(pn, hi, lo);
                int row = m_base + reg, col = 16 * nt + lrow;
                s_phi[row * 232 + col] = hi;
                s_plo[row * 232 + col] = lo;
            }
    }
    __syncthreads();   // P (+pads) ready

    // ---------------- PV (16 waves, exactly 1 tile each)
    {
        const int mtv = w & 3;
        const int ntv = w >> 2;
        f32x4 pacc = {0.f, 0.f, 0.f, 0.f};
        #pragma unroll
        for (int s = 0; s < 7; ++s) {
            bf16x8 ph = *(const bf16x8*)&s_phi[(16 * mtv + lrow) * 232 + 32 * s + kg];
            bf16x8 pl = *(const bf16x8*)&s_plo[(16 * mtv + lrow) * 232 + 32 * s + kg];
            bf16x8 vh = *(const bf16x8*)&s_vhi[(16 * ntv + lrow) * 232 + 32 * s + kg];
            bf16x8 vl = *(const bf16x8*)&s_vlo[(16 * ntv + lrow) * 232 + 32 * s + kg];
            pacc = MFMA16(ph, vh, pacc);
            pacc = MFMA16(ph, vl, pacc);
            pacc = MFMA16(pl, vh, pacc);
        }
        const int vd = 16 * ntv + lrow;
        #pragma unroll
        for (int reg = 0; reg < 4; ++reg) {
            int r = 16 * mtv + g4 + reg;
            if (r < 49) {
                float v = pacc[reg];
                float hs = v * fminf(fmaxf(v + 3.f, 0.f), 6.f) * (1.f / 6.f);
                unsigned short hi, lo; split1(hs, hi, lo);
                int idx = ((b * 49 + r) * 8 + hh) * 64 + vd;
                ao_hi[idx] = hi;
                ao_lo[idx] = lo;
            }
        }
    }
}

// ---------- proj: LDS-staged MFMA GEMM, kc=64, pre-split A (ws) and W (ws)
// grid (256, 4): block = (b, 96-col group). 512 thr, 46 KB LDS -> 3 blocks/CU.
__global__ __launch_bounds__(512, 2)
void levit_proj(const unsigned short* __restrict__ ao_hi,
                const unsigned short* __restrict__ ao_lo,
                const unsigned short* __restrict__ pw_hi,
                const unsigned short* __restrict__ pw_lo,
                const float* __restrict__ pg, const float* __restrict__ pb,
                const float* __restrict__ pm, const float* __restrict__ pv,
                float* __restrict__ out)
{
    __shared__ __align__(16) unsigned short s_a[2 * 64 * 72];   // hi | lo
    __shared__ __align__(16) unsigned short s_w[2 * 96 * 72];

    unsigned short* s_ahi = s_a;          unsigned short* s_alo = s_a + 64 * 72;
    unsigned short* s_whi = s_w;          unsigned short* s_wlo = s_w + 96 * 72;

    const int t = threadIdx.x;
    const int b = blockIdx.x;
    const int cg = blockIdx.y;            // 96-col group (0..3)
    const int l = t & 63;
    const int w = t >> 6;
    const int lrow = l & 15;
    const int kg = (l >> 4) * 8;
    const int g4 = (l >> 4) * 4;

    f32x4 acc[3] = {{0.f,0.f,0.f,0.f},{0.f,0.f,0.f,0.f},{0.f,0.f,0.f,0.f}};

    for (int kc = 0; kc < 512; kc += 64) {
        __syncthreads();
        #pragma unroll
        for (int it = 0; it < 2; ++it) {          // A: 64 rows x 8 b128 x 2 planes = 1024
            int f = t + 512 * it;
            int plane = f >> 9, rem = f & 511;
            int r = rem >> 3, c8 = (rem & 7) * 8;
            const unsigned short* src = plane ? ao_lo : ao_hi;
            unsigned short* dst = plane ? s_alo : s_ahi;
            bf16x8 v = {};
            if (r < 49) v = *(const bf16x8*)&src[(b * 49 + r) * 512 + kc + c8];
            *(bf16x8*)&dst[r * 72 + c8] = v;
        }
        #pragma unroll
        for (int it = 0; it < 3; ++it) {          // W: 96 rows x 8 b128 x 2 planes = 1536
            int f = t + 512 * it;
            int plane = (f >= 768), rem = plane ? f - 768 : f;
            int r = rem >> 3, c8 = (rem & 7) * 8;
            const unsigned short* src = plane ? pw_lo : pw_hi;
            unsigned short* dst = plane ? s_wlo : s_whi;
            *(bf16x8*)&dst[r * 72 + c8] =
                *(const bf16x8*)&src[(cg * 96 + r) * 512 + kc + c8];
        }
        __syncthreads();
        #pragma unroll
        for (int sub = 0; sub < 2; ++sub) {
            int ko = 32 * sub + kg;
            #pragma unroll
            for (int i = 0; i < 3; ++i) {          // 24 tiles, 3 per wave
                int tid3 = 3 * w + i;
                int mt = tid3 & 3, nt = tid3 >> 2;
                bf16x8 ah = *(const bf16x8*)&s_ahi[(16 * mt + lrow) * 72 + ko];
                bf16x8 al = *(const bf16x8*)&s_alo[(16 * mt + lrow) * 72 + ko];
                bf16x8 bh = *(const bf16x8*)&s_whi[(16 * nt + lrow) * 72 + ko];
                bf16x8 bl = *(const bf16x8*)&s_wlo[(16 * nt + lrow) * 72 + ko];
                acc[i] = MFMA16(ah, bh, acc[i]);
                acc[i] = MFMA16(ah, bl, acc[i]);
                acc[i] = MFMA16(al, bh, acc[i]);
            }
        }
    }

    #pragma unroll
    for (int i = 0; i < 3; ++i) {
        int tid3 = 3 * w + i;
        int mt = tid3 & 3, nt = tid3 >> 2;
        int o = cg * 96 + 16 * nt + lrow;
        float iv = pg[o] * rsqrtf(pv[o] + EPS);
        float be = pb[o] - pm[o] * iv;
        #pragma unroll
        for (int reg = 0; reg < 4; ++reg) {
            int r = 16 * mt + g4 + reg;
            if (r < 49) out[(b * 49 + r) * 384 + o] = acc[i][reg] * iv + be;
        }
    }
}

extern "C" void kernel_launch(void* const* d_in, const int* in_sizes, int n_in,
                              void* d_out, int out_size, void* d_ws, size_t ws_size,
                              hipStream_t stream) {
    const float* x     = (const float*)d_in[0];
    const float* kv_w  = (const float*)d_in[1];
    const float* kv_g  = (const float*)d_in[2];
    const float* kv_b  = (const float*)d_in[3];
    const float* kv_m  = (const float*)d_in[4];
    const float* kv_v  = (const float*)d_in[5];
    const float* q_wp  = (const float*)d_in[6];
    const float* q_g   = (const float*)d_in[7];
    const float* q_b   = (const float*)d_in[8];
    const float* q_m   = (const float*)d_in[9];
    const float* q_v   = (const float*)d_in[10];
    const float* pw    = (const float*)d_in[11];
    const float* pg    = (const float*)d_in[12];
    const float* pb    = (const float*)d_in[13];
    const float* pm    = (const float*)d_in[14];
    const float* pv    = (const float*)d_in[15];
    const float* ab    = (const float*)d_in[16];

    // ws layout (27.5 MB, proven in R6):
    unsigned short* ao_hi = (unsigned short*)d_ws;                 // 12544*512
    unsigned short* ao_lo = ao_hi + 12544 * 512;
    unsigned short* wb_hi = ao_lo + 12544 * 512;                   // 8*128*256
    unsigned short* wb_lo = wb_hi + 262144;
    unsigned short* pw_hi = wb_lo + 262144;                        // 384*512
    unsigned short* pw_lo = pw_hi + 196608;

    prep_split<<<1792, 256, 0, stream>>>(kv_w, q_wp, pw, wb_hi, wb_lo, pw_hi, pw_lo);

    dim3 g1(256, 8);   // linear id = b + 256*hh -> same-b heads share an XCD
    levit_fused_attn<<<g1, 1024, 0, stream>>>(x, wb_hi, wb_lo,
                                              kv_g, kv_b, kv_m, kv_v,
                                              q_g, q_b, q_m, q_v, ab, ao_hi, ao_lo);
    levit_proj<<<dim3(256, 4), 512, 0, stream>>>(ao_hi, ao_lo, pw_hi, pw_lo,
                                                 pg, pb, pm, pv, (float*)d_out);
}